// Round 9
// baseline (979.408 us; speedup 1.0000x reference)
//
#include <hip/hip_runtime.h>
#include <stdint.h>

// VQ-VAE vector quantizer — fp32, NCHW input [64,64,32,32], emb [1024,64].
// Single fused kernel (r8-proven math):
//   prologue: block converts its 128 X points to bf16 in LDS + exact A (np)
//   per 256-code chunk: stage E fp32->bf16 in LDS + exact C_k + running emax
//   sweep (single!): bf16 MFMA dk; running threshold thr = min(run,c2min)+W,
//     W = 2*(2^-6*sqrt(A)*emax_so_far + 6e-5)  — proven superset of all k
//     whose EXACT np-fp32 ref distance can be the ref min (r7/r8: absmax 0.0;
//     running emax valid since tested k and current min j are in seen chunks)
//   candidates via __ballot + owner-lane LDS writes (no atomics, no spill)
//   rescue: cnt==1 -> winner; else exact np-fp32 eval; overflow -> full scan
//   epilogue: quantized NCHW + loss + ticket finalize.
constexpr int KCODES = 1024;
constexpr int DDIM   = 64;
constexpr int HW     = 1024;
constexpr int NPTS   = 65536;

constexpr int OUT_Q    = 0;
constexpr int OUT_IDX  = 4194304;
constexpr int OUT_LOSS = 4259840;
constexpr int OUT_NLL  = 4259841;

typedef __attribute__((ext_vector_type(8))) short short8v;
typedef __attribute__((ext_vector_type(4))) float float4v;

__device__ __forceinline__ uint16_t f2bf(float f) {   // RNE fp32->bf16
    uint32_t u = __float_as_uint(f);
    return (uint16_t)((u + 0x7fffu + ((u >> 16) & 1u)) >> 16);
}
__device__ __forceinline__ uint32_t pack2bf(float a, float b) {
    return (uint32_t)f2bf(a) | ((uint32_t)f2bf(b) << 16);
}

__device__ __forceinline__ float np_pairwise_sumsq64(const float* a) {
    float r[8];
    #pragma unroll
    for (int j = 0; j < 8; ++j) r[j] = __fmul_rn(a[j], a[j]);
    #pragma unroll
    for (int i = 8; i < 64; i += 8)
        #pragma unroll
        for (int j = 0; j < 8; ++j)
            r[j] = __fadd_rn(r[j], __fmul_rn(a[i + j], a[i + j]));
    return __fadd_rn(__fadd_rn(__fadd_rn(r[0], r[1]), __fadd_rn(r[2], r[3])),
                     __fadd_rn(__fadd_rn(r[4], r[5]), __fadd_rn(r[6], r[7])));
}

// bit-exact ref distance: d = fp32( fp32(A - 2*G_seq) + C_np ) (r3-proven)
__device__ __forceinline__ float exact_dist(const float* x,
                                            const float* __restrict__ emb,
                                            float A, int k) {
    float e[DDIM];
    const float4* e4 = (const float4*)(emb + (size_t)k * DDIM);
    #pragma unroll
    for (int j = 0; j < 16; ++j) ((float4*)e)[j] = e4[j];
    float C = np_pairwise_sumsq64(e);
    float g = 0.f;
    #pragma unroll
    for (int d = 0; d < DDIM; ++d) g = fmaf(x[d], e[d], g);
    return __fadd_rn(__fsub_rn(A, __fmul_rn(2.0f, g)), C);
}

__global__ void vq_init(float* __restrict__ ws) {
    if (threadIdx.x == 0) { ws[0] = 0.0f; ((unsigned*)ws)[1] = 0u; }
}

constexpr int ROWB = 144;   // padded LDS row bytes (128B data + 16B pad)

__global__ __launch_bounds__(256, 2) void vq_main(
        const float* __restrict__ inp, const float* __restrict__ emb,
        float* __restrict__ ws, float* __restrict__ out, int nblocks)
{
    __shared__ __align__(16) uint16_t sE[256 * (ROWB / 2)];   // 36864 B
    __shared__ __align__(16) uint16_t sXb[128 * (ROWB / 2)];  // 18432 B
    __shared__ float    sC[256];
    __shared__ float    sA[128];
    __shared__ uint16_t sCand[128][16];
    __shared__ int      sCnt[128];
    __shared__ int      sWin[128];
    __shared__ float    sred[4];

    const int tid  = threadIdx.x;
    const int lane = tid & 63;
    const int wave = tid >> 6;
    const int col  = lane & 15;
    const int quad = lane >> 4;
    const int base = blockIdx.x * 128;

    // ---- X prologue: one thread per point (coalesced across hw) ------------
    if (tid < 128) {
        const int n = base + tid, b = n >> 10, hw = n & 1023;
        const float* xin = inp + (size_t)b * DDIM * HW + hw;
        float x[DDIM];
        #pragma unroll
        for (int d = 0; d < DDIM; ++d) x[d] = xin[(size_t)d * HW];
        sA[tid] = np_pairwise_sumsq64(x);
        uint32_t w[32];
        #pragma unroll
        for (int j = 0; j < 32; ++j) w[j] = pack2bf(x[2 * j], x[2 * j + 1]);
        char* xr = (char*)sXb + tid * ROWB;
        #pragma unroll
        for (int j = 0; j < 8; ++j) *(uint4*)(xr + j * 16) = ((uint4*)w)[j];
    }
    __syncthreads();

    // ---- A-fragments (r8-verified layout) ----------------------------------
    short8v a[2][2];
    #pragma unroll
    for (int g = 0; g < 2; ++g) {
        const char* xr = (const char*)sXb + (wave * 32 + g * 16 + col) * ROWB + quad * 16;
        a[g][0] = *(const short8v*)(xr);
        a[g][1] = *(const short8v*)(xr + 64);
    }
    float Ap[2][4], sqA[2][4];
    #pragma unroll
    for (int g = 0; g < 2; ++g)
        #pragma unroll
        for (int r = 0; r < 4; ++r) {
            Ap[g][r]  = sA[wave * 32 + g * 16 + quad * 4 + r];
            sqA[g][r] = sqrtf(Ap[g][r]);
        }

    float run[2][4];
    int   cnt[2][4];
    #pragma unroll
    for (int g = 0; g < 2; ++g)
        #pragma unroll
        for (int r = 0; r < 4; ++r) { run[g][r] = 3.0e38f; cnt[g][r] = 0; }
    float emax2 = 0.f;

    // ---- single sweep over 4 chunks of 256 codes ---------------------------
    #pragma unroll 1
    for (int cc = 0; cc < 4; ++cc) {
        const int K0 = cc * 256;
        __syncthreads();
        // stage E: coalesced fp32 loads, cvt bf16, 8B LDS writes
        const float4* src = (const float4*)(emb + (size_t)K0 * DDIM);
        #pragma unroll
        for (int it = 0; it < 16; ++it) {
            int j = it * 256 + tid, row = j >> 4, pos = j & 15;
            float4 ef = src[j];
            uint2 pk = { pack2bf(ef.x, ef.y), pack2bf(ef.z, ef.w) };
            *(uint2*)((char*)sE + row * ROWB + pos * 8) = pk;
        }
        // exact C_k for this chunk (rows L1-hot from staging)
        {
            float er[DDIM];
            const float4* e4 = (const float4*)(emb + (size_t)(K0 + tid) * DDIM);
            #pragma unroll
            for (int j = 0; j < 16; ++j) ((float4*)er)[j] = e4[j];
            float C = np_pairwise_sumsq64(er);
            sC[tid] = C;
            float m = C;
            #pragma unroll
            for (int off = 32; off > 0; off >>= 1)
                m = fmaxf(m, __shfl_down(m, off, 64));
            if (lane == 0) sred[wave] = m;
        }
        __syncthreads();
        emax2 = fmaxf(emax2, fmaxf(fmaxf(sred[0], sred[1]), fmaxf(sred[2], sred[3])));
        const float emax = sqrtf(emax2);
        float Wv[2][4];
        #pragma unroll
        for (int g = 0; g < 2; ++g)
            #pragma unroll
            for (int r = 0; r < 4; ++r)
                Wv[g][r] = 2.0f * (0.015625f * sqA[g][r] * emax + 6e-5f);

        #pragma unroll 2
        for (int c2 = 0; c2 < 16; ++c2) {
            const int kcL = c2 * 16 + col;
            const char* eptr = (const char*)sE + kcL * ROWB + quad * 16;
            short8v b0 = *(const short8v*)(eptr);
            short8v b1 = *(const short8v*)(eptr + 64);
            float Ck = sC[kcL];
            #pragma unroll
            for (int g = 0; g < 2; ++g) {
                float4v acc = {0.f, 0.f, 0.f, 0.f};
                acc = __builtin_amdgcn_mfma_f32_16x16x32_bf16(a[g][0], b0, acc, 0, 0, 0);
                acc = __builtin_amdgcn_mfma_f32_16x16x32_bf16(a[g][1], b1, acc, 0, 0, 0);
                #pragma unroll
                for (int r = 0; r < 4; ++r) {
                    float dk = fmaf(-2.0f, acc[r], Ap[g][r]) + Ck;
                    float m = dk;                         // cross-col min (this c2)
                    m = fminf(m, __shfl_xor(m, 1, 16));
                    m = fminf(m, __shfl_xor(m, 2, 16));
                    m = fminf(m, __shfl_xor(m, 4, 16));
                    m = fminf(m, __shfl_xor(m, 8, 16));
                    run[g][r] = fminf(run[g][r], m);
                    unsigned long long bm = __ballot(dk <= run[g][r] + Wv[g][r]);
                    if (col == 0) {                       // sole owner of (g,quad,r)
                        unsigned gm = (unsigned)(bm >> (quad * 16)) & 0xffffu;
                        while (gm) {
                            int bit = __ffs(gm) - 1;
                            gm &= gm - 1;
                            int ct = cnt[g][r];
                            if (ct < 16)
                                sCand[wave * 32 + g * 16 + quad * 4 + r][ct] =
                                    (uint16_t)(K0 + c2 * 16 + bit);
                            cnt[g][r] = ct + 1;
                        }
                    }
                }
            }
        }
    }
    if (col == 0) {
        #pragma unroll
        for (int g = 0; g < 2; ++g)
            #pragma unroll
            for (int r = 0; r < 4; ++r)
                sCnt[wave * 32 + g * 16 + quad * 4 + r] = cnt[g][r];
    }
    __syncthreads();

    // ---- rescue: exact np-fp32 on candidates -------------------------------
    if (tid < 128) {
        const int p = tid, n = base + p, c = sCnt[p];
        int win;
        if (c == 1) {
            win = sCand[p][0];           // superset window => sole cand is argmin
        } else {
            const int b = n >> 10, hw = n & 1023;
            const float* xin = inp + (size_t)b * DDIM * HW + hw;
            float x[DDIM];
            #pragma unroll
            for (int d = 0; d < DDIM; ++d) x[d] = xin[(size_t)d * HW];
            const float A = sA[p];
            float bd = 3.0e38f; win = 0;
            if (c >= 2 && c <= 16) {
                win = KCODES - 1;
                #pragma unroll 1
                for (int i = 0; i < c; ++i) {
                    int k = sCand[p][i];
                    float dd = exact_dist(x, emb, A, k);
                    if (dd < bd || (dd == bd && k < win)) { bd = dd; win = k; }
                }
            } else {                     // overflow (or impossible 0): full scan
                #pragma unroll 1
                for (int k = 0; k < KCODES; ++k) {
                    float dd = exact_dist(x, emb, A, k);
                    if (dd < bd) { bd = dd; win = k; }
                }
            }
        }
        sWin[p] = win;
        out[OUT_IDX + n] = (float)win;
    }
    __syncthreads();

    // ---- epilogue: quantized NCHW + loss (r8-proven) ------------------------
    {
        const int pl = tid & 127, half = tid >> 7;
        const int n2 = base + pl, b2 = n2 >> 10, hw2 = n2 & 1023;
        const int win = sWin[pl];
        float q[32];
        const float4* q4 = (const float4*)(emb + (size_t)win * DDIM + half * 32);
        #pragma unroll
        for (int j = 0; j < 8; ++j) ((float4*)q)[j] = q4[j];
        const float* xin2 = inp + (size_t)b2 * DDIM * HW + hw2 + (size_t)half * 32 * HW;
        float* orow = out + (size_t)b2 * DDIM * HW + hw2 + (size_t)half * 32 * HW;
        float lacc = 0.f;
        #pragma unroll
        for (int j = 0; j < 32; ++j) {
            float xv = xin2[(size_t)j * HW];
            float diff = __fsub_rn(q[j], xv);
            orow[(size_t)j * HW] = __fadd_rn(xv, diff);   // ref's x + (q - x)
            lacc = fmaf(diff, diff, lacc);
        }
        #pragma unroll
        for (int off = 32; off > 0; off >>= 1) lacc += __shfl_down(lacc, off, 64);
        if (lane == 0) sred[wave] = lacc;
    }
    __syncthreads();
    if (tid == 0) {
        atomicAdd(ws, sred[0] + sred[1] + sred[2] + sred[3]);
        __threadfence();
        unsigned old = atomicAdd((unsigned*)ws + 1, 1u);
        if (old == (unsigned)(nblocks - 1)) {
            __threadfence();
            float L = __hip_atomic_load(ws, __ATOMIC_RELAXED,
                                        __HIP_MEMORY_SCOPE_AGENT);
            out[OUT_LOSS] = L * (1.25f / 4194304.0f);
            out[OUT_NLL]  = 1.0f;
        }
    }
}

extern "C" void kernel_launch(void* const* d_in, const int* in_sizes, int n_in,
                              void* d_out, int out_size, void* d_ws, size_t ws_size,
                              hipStream_t stream) {
    const float* inp = (const float*)d_in[0];
    const float* emb = (const float*)d_in[1];
    float* out = (float*)d_out;
    float* ws  = (float*)d_ws;

    vq_init<<<1, 64, 0, stream>>>(ws);
    vq_main<<<NPTS / 128, 256, 0, stream>>>(inp, emb, ws, out, NPTS / 128);
}

// Round 10
// 157.362 us; speedup vs baseline: 6.2239x; 6.2239x over previous
//
#include <hip/hip_runtime.h>
#include <stdint.h>

// VQ-VAE vector quantizer — fp32, NCHW input [64,64,32,32], emb [1024,64].
// Fused single hot kernel; r8-proven two-sweep math:
//   prologue: block converts its 128 X points to bf16 in LDS + exact A (np)
//   sweep1 (per 256-code chunk: stage E fp32->bf16 in LDS, exact np C_k into
//     persistent sC[1024], accumulate emax): MFMA dk -> per-point dmin (regs,
//     pure fminf — no shfl/ballot in inner loop)
//   thr = dmin + 2*(2^-6*sqrt(A)*emax + 6e-5)  [r7/r8-proven superset window
//     for the EXACT np-fp32 ref argmin, absmax 0.0 twice]
//   sweep2: re-stage E, ballot vs FIXED thr, owner-lane LDS collect (no
//     atomics; final-dmin window => lambda~0.4 extras, cap-16 never hit)
//   rescue: cnt==1 -> winner (71% of points); else exact np-fp32 eval with
//     C_k from sC; overflow safety -> full exact scan
//   epilogue: quantized NCHW + loss + ticket finalize.
constexpr int KCODES = 1024;
constexpr int DDIM   = 64;
constexpr int HW     = 1024;
constexpr int NPTS   = 65536;

constexpr int OUT_Q    = 0;
constexpr int OUT_IDX  = 4194304;
constexpr int OUT_LOSS = 4259840;
constexpr int OUT_NLL  = 4259841;

typedef __attribute__((ext_vector_type(8))) short short8v;
typedef __attribute__((ext_vector_type(4))) float float4v;

__device__ __forceinline__ uint16_t f2bf(float f) {   // RNE fp32->bf16
    uint32_t u = __float_as_uint(f);
    return (uint16_t)((u + 0x7fffu + ((u >> 16) & 1u)) >> 16);
}
__device__ __forceinline__ uint32_t pack2bf(float a, float b) {
    return (uint32_t)f2bf(a) | ((uint32_t)f2bf(b) << 16);
}

__device__ __forceinline__ float np_pairwise_sumsq64(const float* a) {
    float r[8];
    #pragma unroll
    for (int j = 0; j < 8; ++j) r[j] = __fmul_rn(a[j], a[j]);
    #pragma unroll
    for (int i = 8; i < 64; i += 8)
        #pragma unroll
        for (int j = 0; j < 8; ++j)
            r[j] = __fadd_rn(r[j], __fmul_rn(a[i + j], a[i + j]));
    return __fadd_rn(__fadd_rn(__fadd_rn(r[0], r[1]), __fadd_rn(r[2], r[3])),
                     __fadd_rn(__fadd_rn(r[4], r[5]), __fadd_rn(r[6], r[7])));
}

__global__ void vq_init(float* __restrict__ ws) {
    if (threadIdx.x == 0) { ws[0] = 0.0f; ((unsigned*)ws)[1] = 0u; }
}

constexpr int ROWB = 144;   // padded LDS row bytes (128B data + 16B pad)

__global__ __launch_bounds__(256, 2) void vq_main(
        const float* __restrict__ inp, const float* __restrict__ emb,
        float* __restrict__ ws, float* __restrict__ out, int nblocks)
{
    __shared__ __align__(16) uint16_t sE[256 * (ROWB / 2)];   // 36864 B
    __shared__ __align__(16) uint16_t sXb[128 * (ROWB / 2)];  // 18432 B
    __shared__ float    sC[KCODES];                           // 4096 B (persistent)
    __shared__ float    sA[128];
    __shared__ uint16_t sCand[128][16];
    __shared__ int      sCnt[128];
    __shared__ int      sWin[128];
    __shared__ float    sred[4];

    const int tid  = threadIdx.x;
    const int lane = tid & 63;
    const int wave = tid >> 6;
    const int col  = lane & 15;
    const int quad = lane >> 4;
    const int base = blockIdx.x * 128;

    // ---- X prologue: one thread per point (512B-coalesced per d) ------------
    if (tid < 128) {
        const int n = base + tid, b = n >> 10, hw = n & 1023;
        const float* xin = inp + (size_t)b * DDIM * HW + hw;
        float x[DDIM];
        #pragma unroll
        for (int d = 0; d < DDIM; ++d) x[d] = xin[(size_t)d * HW];
        sA[tid] = np_pairwise_sumsq64(x);
        uint32_t w[32];
        #pragma unroll
        for (int j = 0; j < 32; ++j) w[j] = pack2bf(x[2 * j], x[2 * j + 1]);
        char* xr = (char*)sXb + tid * ROWB;
        #pragma unroll
        for (int j = 0; j < 8; ++j) *(uint4*)(xr + j * 16) = ((uint4*)w)[j];
    }
    __syncthreads();

    // ---- A-fragments (r8-verified layout) -----------------------------------
    short8v a[2][2];
    #pragma unroll
    for (int g = 0; g < 2; ++g) {
        const char* xr = (const char*)sXb + (wave * 32 + g * 16 + col) * ROWB + quad * 16;
        a[g][0] = *(const short8v*)(xr);
        a[g][1] = *(const short8v*)(xr + 64);
    }
    float Ap[2][4];
    #pragma unroll
    for (int g = 0; g < 2; ++g)
        #pragma unroll
        for (int r = 0; r < 4; ++r)
            Ap[g][r] = sA[wave * 32 + g * 16 + quad * 4 + r];

    // ---- sweep 1: dmin (pure fminf inner loop) ------------------------------
    float run[2][4];
    #pragma unroll
    for (int g = 0; g < 2; ++g)
        #pragma unroll
        for (int r = 0; r < 4; ++r) run[g][r] = 3.0e38f;
    float emax2 = 0.f;

    #pragma unroll 1
    for (int cc = 0; cc < 4; ++cc) {
        const int K0 = cc * 256;
        __syncthreads();
        const float4* src = (const float4*)(emb + (size_t)K0 * DDIM);
        #pragma unroll
        for (int it = 0; it < 16; ++it) {
            int j = it * 256 + tid, row = j >> 4, pos = j & 15;
            float4 ef = src[j];
            uint2 pk = { pack2bf(ef.x, ef.y), pack2bf(ef.z, ef.w) };
            *(uint2*)((char*)sE + row * ROWB + pos * 8) = pk;
        }
        {   // exact np C_k for code K0+tid (rows L1-hot from staging)
            float er[DDIM];
            const float4* e4 = (const float4*)(emb + (size_t)(K0 + tid) * DDIM);
            #pragma unroll
            for (int j = 0; j < 16; ++j) ((float4*)er)[j] = e4[j];
            float C = np_pairwise_sumsq64(er);
            sC[K0 + tid] = C;
            float m = C;
            #pragma unroll
            for (int off = 32; off > 0; off >>= 1)
                m = fmaxf(m, __shfl_down(m, off, 64));
            if (lane == 0) sred[wave] = m;
        }
        __syncthreads();
        emax2 = fmaxf(emax2, fmaxf(fmaxf(sred[0], sred[1]), fmaxf(sred[2], sred[3])));

        #pragma unroll 2
        for (int c2 = 0; c2 < 16; ++c2) {
            const int kcL = c2 * 16 + col;
            const char* eptr = (const char*)sE + kcL * ROWB + quad * 16;
            short8v b0 = *(const short8v*)(eptr);
            short8v b1 = *(const short8v*)(eptr + 64);
            float Ck = sC[K0 + kcL];
            #pragma unroll
            for (int g = 0; g < 2; ++g) {
                float4v acc = {0.f, 0.f, 0.f, 0.f};
                acc = __builtin_amdgcn_mfma_f32_16x16x32_bf16(a[g][0], b0, acc, 0, 0, 0);
                acc = __builtin_amdgcn_mfma_f32_16x16x32_bf16(a[g][1], b1, acc, 0, 0, 0);
                #pragma unroll
                for (int r = 0; r < 4; ++r) {
                    float dk = fmaf(-2.0f, acc[r], Ap[g][r]) + Ck;
                    run[g][r] = fminf(run[g][r], dk);
                }
            }
        }
    }

    // ---- fixed threshold from final dmin + global emax ----------------------
    const float emax = sqrtf(emax2);
    float thr[2][4];
    #pragma unroll
    for (int g = 0; g < 2; ++g)
        #pragma unroll
        for (int r = 0; r < 4; ++r) {
            float m = run[g][r];
            m = fminf(m, __shfl_xor(m, 1, 16));
            m = fminf(m, __shfl_xor(m, 2, 16));
            m = fminf(m, __shfl_xor(m, 4, 16));
            m = fminf(m, __shfl_xor(m, 8, 16));
            thr[g][r] = m + 2.0f * (0.015625f * sqrtf(Ap[g][r]) * emax + 6e-5f);
        }

    // ---- sweep 2: candidates (ballot vs fixed thr, owner-lane writes) -------
    int cnt[2][4];
    #pragma unroll
    for (int g = 0; g < 2; ++g)
        #pragma unroll
        for (int r = 0; r < 4; ++r) cnt[g][r] = 0;

    #pragma unroll 1
    for (int cc = 0; cc < 4; ++cc) {
        const int K0 = cc * 256;
        __syncthreads();
        const float4* src = (const float4*)(emb + (size_t)K0 * DDIM);
        #pragma unroll
        for (int it = 0; it < 16; ++it) {
            int j = it * 256 + tid, row = j >> 4, pos = j & 15;
            float4 ef = src[j];
            uint2 pk = { pack2bf(ef.x, ef.y), pack2bf(ef.z, ef.w) };
            *(uint2*)((char*)sE + row * ROWB + pos * 8) = pk;
        }
        __syncthreads();

        #pragma unroll 1
        for (int c2 = 0; c2 < 16; ++c2) {
            const int kcL = c2 * 16 + col;
            const char* eptr = (const char*)sE + kcL * ROWB + quad * 16;
            short8v b0 = *(const short8v*)(eptr);
            short8v b1 = *(const short8v*)(eptr + 64);
            float Ck = sC[K0 + kcL];
            #pragma unroll
            for (int g = 0; g < 2; ++g) {
                float4v acc = {0.f, 0.f, 0.f, 0.f};
                acc = __builtin_amdgcn_mfma_f32_16x16x32_bf16(a[g][0], b0, acc, 0, 0, 0);
                acc = __builtin_amdgcn_mfma_f32_16x16x32_bf16(a[g][1], b1, acc, 0, 0, 0);
                #pragma unroll
                for (int r = 0; r < 4; ++r) {
                    float dk = fmaf(-2.0f, acc[r], Ap[g][r]) + Ck;
                    unsigned long long bm = __ballot(dk <= thr[g][r]);
                    if (col == 0) {               // sole owner of point (g,quad,r)
                        unsigned gm = (unsigned)(bm >> (quad * 16)) & 0xffffu;
                        while (gm) {
                            int bit = __ffs(gm) - 1;
                            gm &= gm - 1;
                            int ct = cnt[g][r];
                            if (ct < 16)
                                sCand[wave * 32 + g * 16 + quad * 4 + r][ct] =
                                    (uint16_t)(K0 + c2 * 16 + bit);
                            cnt[g][r] = ct + 1;
                        }
                    }
                }
            }
        }
    }
    if (col == 0) {
        #pragma unroll
        for (int g = 0; g < 2; ++g)
            #pragma unroll
            for (int r = 0; r < 4; ++r)
                sCnt[wave * 32 + g * 16 + quad * 4 + r] = cnt[g][r];
    }
    __syncthreads();

    // ---- rescue: exact np-fp32 on candidates (C_k from sC) ------------------
    if (tid < 128) {
        const int p = tid, n = base + p, c = sCnt[p];
        int win;
        if (c == 1) {
            win = sCand[p][0];           // superset window => sole cand is argmin
        } else {
            const int b = n >> 10, hw = n & 1023;
            const float* xin = inp + (size_t)b * DDIM * HW + hw;
            float x[DDIM];
            #pragma unroll
            for (int d = 0; d < DDIM; ++d) x[d] = xin[(size_t)d * HW];
            const float A = sA[p];
            float bd = 3.0e38f; win = 0;
            if (c >= 2 && c <= 16) {
                win = KCODES - 1;
                #pragma unroll 1
                for (int i = 0; i < c; ++i) {
                    int k = sCand[p][i];
                    float e[DDIM];
                    const float4* e4 = (const float4*)(emb + (size_t)k * DDIM);
                    #pragma unroll
                    for (int j = 0; j < 16; ++j) ((float4*)e)[j] = e4[j];
                    float g = 0.f;
                    #pragma unroll
                    for (int d = 0; d < DDIM; ++d) g = fmaf(x[d], e[d], g);
                    float dd = __fadd_rn(__fsub_rn(A, __fmul_rn(2.0f, g)), sC[k]);
                    if (dd < bd || (dd == bd && k < win)) { bd = dd; win = k; }
                }
            } else {                     // overflow safety: full exact scan
                #pragma unroll 1
                for (int k = 0; k < KCODES; ++k) {
                    float e[DDIM];
                    const float4* e4 = (const float4*)(emb + (size_t)k * DDIM);
                    #pragma unroll
                    for (int j = 0; j < 16; ++j) ((float4*)e)[j] = e4[j];
                    float g = 0.f;
                    #pragma unroll
                    for (int d = 0; d < DDIM; ++d) g = fmaf(x[d], e[d], g);
                    float dd = __fadd_rn(__fsub_rn(A, __fmul_rn(2.0f, g)), sC[k]);
                    if (dd < bd) { bd = dd; win = k; }
                }
            }
        }
        sWin[p] = win;
        out[OUT_IDX + n] = (float)win;
    }
    __syncthreads();

    // ---- epilogue: quantized NCHW + loss (r8-proven) -------------------------
    {
        const int pl = tid & 127, half = tid >> 7;
        const int n2 = base + pl, b2 = n2 >> 10, hw2 = n2 & 1023;
        const int win = sWin[pl];
        float q[32];
        const float4* q4 = (const float4*)(emb + (size_t)win * DDIM + half * 32);
        #pragma unroll
        for (int j = 0; j < 8; ++j) ((float4*)q)[j] = q4[j];
        const float* xin2 = inp + (size_t)b2 * DDIM * HW + hw2 + (size_t)half * 32 * HW;
        float* orow = out + (size_t)b2 * DDIM * HW + hw2 + (size_t)half * 32 * HW;
        float lacc = 0.f;
        #pragma unroll
        for (int j = 0; j < 32; ++j) {
            float xv = xin2[(size_t)j * HW];
            float diff = __fsub_rn(q[j], xv);
            orow[(size_t)j * HW] = __fadd_rn(xv, diff);   // ref's x + (q - x)
            lacc = fmaf(diff, diff, lacc);
        }
        #pragma unroll
        for (int off = 32; off > 0; off >>= 1) lacc += __shfl_down(lacc, off, 64);
        if (lane == 0) sred[wave] = lacc;
    }
    __syncthreads();
    if (tid == 0) {
        atomicAdd(ws, sred[0] + sred[1] + sred[2] + sred[3]);
        __threadfence();
        unsigned old = atomicAdd((unsigned*)ws + 1, 1u);
        if (old == (unsigned)(nblocks - 1)) {
            __threadfence();
            float L = __hip_atomic_load(ws, __ATOMIC_RELAXED,
                                        __HIP_MEMORY_SCOPE_AGENT);
            out[OUT_LOSS] = L * (1.25f / 4194304.0f);
            out[OUT_NLL]  = 1.0f;
        }
    }
}

extern "C" void kernel_launch(void* const* d_in, const int* in_sizes, int n_in,
                              void* d_out, int out_size, void* d_ws, size_t ws_size,
                              hipStream_t stream) {
    const float* inp = (const float*)d_in[0];
    const float* emb = (const float*)d_in[1];
    float* out = (float*)d_out;
    float* ws  = (float*)d_ws;

    vq_init<<<1, 64, 0, stream>>>(ws);
    vq_main<<<NPTS / 128, 256, 0, stream>>>(inp, emb, ws, out, NPTS / 128);
}